// Round 16
// baseline (55.909 us; speedup 1.0000x reference)
//
#include <hip/hip_runtime.h>
#include <hip/hip_bf16.h>

#define BB 64
#define NN 96
#define FF 16
#define HH 128
#define KK 64
#define LL 3
#define CUTOFF_F 10.0f
#define GAMMA_F 10.0f

#define W3_BLOCKS 99
#define CNT_BLOCKS BB

// ---------------------------------------------------------------------------
// pre_kernel:
//   [0,99):   W3 = (Wrbf@Wpair)@Wa1 rows, ROW-MAJOR [l][k][h] (row 64 -> c3)
//   [99,163): cnt[b]; zero out[b]
// (no weight interleaving needed: c=4 tile reads natural float4 rows)
// ---------------------------------------------------------------------------
__global__ __launch_bounds__(256) void pre_kernel(
    const float* __restrict__ Wrbf, const float* __restrict__ brbf,
    const float* __restrict__ Wpair, const float* __restrict__ bpair,
    const float* __restrict__ Wa1,
    const int* __restrict__ batch,
    float* __restrict__ W3i, float* __restrict__ c3,
    float* __restrict__ cnt, float* __restrict__ out)
{
    const int bid = blockIdx.x;
    const int tid = threadIdx.x;
    if (bid < W3_BLOCKS) {
        __shared__ float sW2[2][HH];
        const int l    = bid / 33;
        const int r0   = (bid % 33) * 2;
        const int half = tid >> 7;
        const int h    = tid & 127;
        const int kk   = r0 + half;       // 0..65 (65 inactive)
        const bool active = (kk <= KK);
        if (active) {
            const float* Wp = Wpair + l * HH * HH + h;
            const float* arow;
            float acc;
            if (kk < KK) { arow = Wrbf + (l * KK + kk) * HH; acc = 0.f; }
            else         { arow = brbf + l * HH;             acc = bpair[l * HH + h]; }
            #pragma unroll 8
            for (int m = 0; m < HH; ++m) acc += arow[m] * Wp[m * HH];
            sW2[half][h] = acc;
        }
        __syncthreads();
        if (active) {
            const float* Wa = Wa1 + l * HH * HH + h;
            const float* row = sW2[half];
            float a3 = 0.f;
            #pragma unroll 8
            for (int m = 0; m < HH; ++m) a3 += row[m] * Wa[m * HH];
            if (kk < KK) W3i[l * KK * HH + kk * HH + h] = a3;
            else         c3[l * HH + h] = a3;
        }
    } else {
        int b = bid - W3_BLOCKS;
        __shared__ int c[4];
        bool v = (tid < NN) && (batch[b * NN + tid] != -1);
        unsigned long long m = __ballot(v);
        if ((tid & 63) == 0) c[tid >> 6] = __popcll(m);
        __syncthreads();
        if (tid == 0) {
            cnt[b] = (float)(c[0] + c[1] + c[2] + c[3]);
            out[b] = 0.f;
        }
    }
}

// ---------------------------------------------------------------------------
// chain_kernel: AT=24, 256 thr (4 waves), grid 256 = 1 block/CU.
// Thread tile 4ch x 3at: cp=q&31 -> channels 4cp..4cp+3; ap=q>>5, wave wv ->
// atoms 6wv+3ap..+2. Per k-quad: 4 weight b128 (row-major float4, upper half
// broadcasts) + 3 operand b128 broadcasts = 7 LDS reads / 48 FMA.
// R15-proven 4-slot x 16KB ring, counted vmcnt(8), one s_barrier/phase,
// stage-after-barrier, epilogue 8/4/0. Wa2/Wo1 DMA'd RAW from inputs.
// ---------------------------------------------------------------------------
#define AT 24
#define CHF 4096              // floats per 16KB chunk (32 k-rows x 128 ch)
#define SSW 68                // sST row stride
#define TBW 132               // tbT row stride

typedef const __attribute__((address_space(1))) void* gp1_t;
typedef __attribute__((address_space(3))) void* lp3_t;

__device__ __forceinline__ void stage16k(const float* g, float* lds, int tid)
{
    const int lane = tid & 63, wvq = tid >> 6;
    #pragma unroll
    for (int j = 0; j < 4; ++j) {
        const int base = j * 256 + wvq * 64;           // float4 units
        __builtin_amdgcn_global_load_lds((gp1_t)(g + (size_t)(base + lane) * 4),
                                         (lp3_t)(lds + (size_t)base * 4), 16, 0, 0);
    }
}

// phase boundary: publish loads (vmcnt<=N) + flush LDS writes, then barrier.
#define BND(VM) do {                                                        \
    asm volatile("s_waitcnt vmcnt(" VM ") lgkmcnt(0)" ::: "memory");        \
    __builtin_amdgcn_s_barrier();                                           \
    __builtin_amdgcn_sched_barrier(0);                                      \
} while (0)

__device__ __forceinline__ float silu1(float v) { return v / (1.f + __expf(-v)); }

// one 16KB chunk (32 k) of a GEMM. ACC[a*4+c]: atom a (0..2), channel c (0..3)
#define GEMM12(ACC, WBP, SRC, KB) do {                                      \
    _Pragma("unroll")                                                       \
    for (int kq = 0; kq < 8; ++kq) {                                        \
        float4 w0 = *(const float4*)&(WBP)[(4 * kq + 0) * HH + c0];         \
        float4 w1 = *(const float4*)&(WBP)[(4 * kq + 1) * HH + c0];         \
        float4 w2 = *(const float4*)&(WBP)[(4 * kq + 2) * HH + c0];         \
        float4 w3 = *(const float4*)&(WBP)[(4 * kq + 3) * HH + c0];         \
        float4 u0 = *(const float4*)&SRC[at0 + 0][(KB) + 4 * kq];           \
        float4 u1 = *(const float4*)&SRC[at0 + 1][(KB) + 4 * kq];           \
        float4 u2 = *(const float4*)&SRC[at0 + 2][(KB) + 4 * kq];           \
        ACC[0]  += w0.x*u0.x + w1.x*u0.y + w2.x*u0.z + w3.x*u0.w;           \
        ACC[1]  += w0.y*u0.x + w1.y*u0.y + w2.y*u0.z + w3.y*u0.w;           \
        ACC[2]  += w0.z*u0.x + w1.z*u0.y + w2.z*u0.z + w3.z*u0.w;           \
        ACC[3]  += w0.w*u0.x + w1.w*u0.y + w2.w*u0.z + w3.w*u0.w;           \
        ACC[4]  += w0.x*u1.x + w1.x*u1.y + w2.x*u1.z + w3.x*u1.w;           \
        ACC[5]  += w0.y*u1.x + w1.y*u1.y + w2.y*u1.z + w3.y*u1.w;           \
        ACC[6]  += w0.z*u1.x + w1.z*u1.y + w2.z*u1.z + w3.z*u1.w;           \
        ACC[7]  += w0.w*u1.x + w1.w*u1.y + w2.w*u1.z + w3.w*u1.w;           \
        ACC[8]  += w0.x*u2.x + w1.x*u2.y + w2.x*u2.z + w3.x*u2.w;           \
        ACC[9]  += w0.y*u2.x + w1.y*u2.y + w2.y*u2.z + w3.y*u2.w;           \
        ACC[10] += w0.z*u2.x + w1.z*u2.y + w2.z*u2.z + w3.z*u2.w;           \
        ACC[11] += w0.w*u2.x + w1.w*u2.y + w2.w*u2.z + w3.w*u2.w;           \
    }                                                                       \
} while (0)

__global__ __launch_bounds__(256, 1) void chain_kernel(
    const float* __restrict__ X, const float* __restrict__ R,
    const float* __restrict__ We, const float* __restrict__ be,
    const float* __restrict__ ba1, const float* __restrict__ ba2,
    const float* __restrict__ bo1, const float* __restrict__ Wo2,
    const float* __restrict__ bo2, const float* __restrict__ W3i,
    const float* __restrict__ Wa2, const float* __restrict__ Wo1,
    const float* __restrict__ c3, const float* __restrict__ cnt,
    float* __restrict__ out)
{
    __shared__ __align__(16) float wb[4][CHF];     // 64KB weight ring
    __shared__ __align__(16) float sST[AT][SSW];   // 6.5KB S, atom-major
    __shared__ __align__(16) float tbT[AT][TBW];   // 12.7KB t/h (sD/sRf alias)
    __shared__ __align__(16) float sX[FF][AT];     // 1.5KB
    __shared__ float po[8][3];

    const int tid = threadIdx.x;
    const int q   = tid & 63;            // lane
    const int wv  = tid >> 6;            // wave 0..3
    const int cp  = q & 31;              // channel quad index
    const int ap  = q >> 5;              // atom-triple half
    const int c0  = 4 * cp;              // channels c0..c0+3
    const int at0 = 6 * wv + 3 * ap;     // atoms at0..at0+2
    const int a0  = blockIdx.x * AT;     // 96 % 24 == 0 -> block within one molecule
    const int b   = a0 / NN;
    const int lbase = a0 - b * NN;       // molecule-local first atom
    const float cb = cnt[b];
    const int nv  = (int)cb;             // valid atoms = molecule-local prefix

    float* sD  = &tbT[0][0];             // 2304 floats distances (alias, dead later)
    float* sRf = sD + AT * NN;           // 288 floats molecule R (2592 <= 3168)

    // ---- stage molecule R, X^T ----
    for (int t = tid; t < NN * 3; t += 256) sRf[t] = R[b * NN * 3 + t];
    for (int t = tid; t < AT * FF; t += 256) {
        int a = t >> 4, f = t & 15;
        sX[f][a] = X[(a0 + a) * FF + f];
    }
    __syncthreads();

    // ---- phase 1: distance table D[j][i] ----
    for (int e = tid; e < AT * NN; e += 256) {
        int j = e / NN, i = e - j * NN;
        float dx = sRf[i * 3 + 0] - sRf[(lbase + j) * 3 + 0];
        float dy = sRf[i * 3 + 1] - sRf[(lbase + j) * 3 + 1];
        float dz = sRf[i * 3 + 2] - sRf[(lbase + j) * 3 + 2];
        sD[e] = sqrtf(dx * dx + dy * dy + dz * dz);
    }
    __syncthreads();   // no DMA outstanding yet -> cheap

    // ---- bias preloads (float4 per channel quad, BEFORE chunk DMAs) ----
    const float4 beR  = *(const float4*)&be[c0];
    const float4 bo1R = *(const float4*)&bo1[c0];
    const float4 wo2R = *(const float4*)&Wo2[c0];
    const float  bo2R = bo2[0];
    const float4 c3R0 = *(const float4*)&c3[0 * HH + c0];
    const float4 c3R1 = *(const float4*)&c3[1 * HH + c0];
    const float4 c3R2 = *(const float4*)&c3[2 * HH + c0];
    const float4 ba1R0 = *(const float4*)&ba1[0 * HH + c0];
    const float4 ba1R1 = *(const float4*)&ba1[1 * HH + c0];
    const float4 ba1R2 = *(const float4*)&ba1[2 * HH + c0];
    const float4 ba2R0 = *(const float4*)&ba2[0 * HH + c0];
    const float4 ba2R1 = *(const float4*)&ba2[1 * HH + c0];
    const float4 ba2R2 = *(const float4*)&ba2[2 * HH + c0];

    // ---- prologue: issue chunks 0..3 (hidden under S-phase) ----
    stage16k(W3i,        wb[0], tid);    // chunk 0: W3[0] k 0-31
    stage16k(W3i + CHF,  wb[1], tid);    // chunk 1: W3[0] k 32-63
    stage16k(Wa2,        wb[2], tid);    // chunk 2: Wa2[0] m 0-31 (raw input)
    stage16k(Wa2 + CHF,  wb[3], tid);    // chunk 3: Wa2[0] m 32-63

    // ---- phase 2: sST[j][k] = sum_{i<nv} exp(-g*(D[j][i]-ck)^2) ----
    {
        const int k = q;
        const float ck = (float)k * (CUTOFF_F / (float)(KK - 1));
        #pragma unroll
        for (int r = 0; r < 6; ++r) {
            int j = 6 * wv + r;              // wave-uniform
            if (lbase + j >= nv) { sST[j][k] = 0.f; continue; }
            const float* Dr = sD + j * NN;
            float acc = 0.f;
            for (int i = 0; i < nv; ++i) {
                float u = Dr[i] - ck;
                acc += __expf(-GAMMA_F * u * u);
            }
            sST[j][k] = acc;
        }
    }

    // ---- embedding: h[a*4+c] = X@We + be ----
    float h[12];
    {
        float acc[12] = {0,0,0,0,0,0,0,0,0,0,0,0};
        #pragma unroll
        for (int f = 0; f < FF; ++f) {
            float4 w4 = *(const float4*)&We[f * HH + c0];
            #pragma unroll
            for (int a = 0; a < 3; ++a) {
                float x = sX[f][at0 + a];
                acc[a * 4 + 0] += w4.x * x; acc[a * 4 + 1] += w4.y * x;
                acc[a * 4 + 2] += w4.z * x; acc[a * 4 + 3] += w4.w * x;
            }
        }
        #pragma unroll
        for (int a = 0; a < 3; ++a) {
            h[a * 4 + 0] = acc[a * 4 + 0] + beR.x;
            h[a * 4 + 1] = acc[a * 4 + 1] + beR.y;
            h[a * 4 + 2] = acc[a * 4 + 2] + beR.z;
            h[a * 4 + 3] = acc[a * 4 + 3] + beR.w;
        }
    }

    BND("12");   // chunk 0 landed everywhere (1,2,3 still in flight)

    // ---- layers: phases 6l+0 .. 6l+5 (NOT unrolled -> no spills) ----
    #pragma unroll 1
    for (int l = 0; l < LL; ++l) {
        const float4 c3v  = (l == 0) ? c3R0  : (l == 1) ? c3R1  : c3R2;
        const float4 ba1v = (l == 0) ? ba1R0 : (l == 1) ? ba1R1 : ba1R2;
        const float4 ba2v = (l == 0) ? ba2R0 : (l == 1) ? ba2R1 : ba2R2;
        const float* WaN = (l < LL - 1) ? (Wa2 + (l + 1) * HH * HH) : (Wo1 + 2 * CHF);
        const float* W3N = (l < LL - 1) ? (W3i + (l + 1) * KK * HH) : Wo1;
        const float* WaL = Wa2 + l * HH * HH;

        // GEMM1: acc = S @ W3[l]
        float acc[12] = {0,0,0,0,0,0,0,0,0,0,0,0};
        GEMM12(acc, (&wb[(6 * l + 0) & 3][0]), sST, 0);       // phase 6l+0
        BND("8"); stage16k(WaL + 2 * CHF, &wb[(6 * l + 4) & 3][0], tid);
        GEMM12(acc, (&wb[(6 * l + 1) & 3][0]), sST, 32);      // phase 6l+1
        {   // silu -> tbT (owned (atom, ch-quad) cells; last readers done)
            #pragma unroll
            for (int a = 0; a < 3; ++a) {
                float4 t4;
                t4.x = silu1(acc[a * 4 + 0] + cb * c3v.x + ba1v.x);
                t4.y = silu1(acc[a * 4 + 1] + cb * c3v.y + ba1v.y);
                t4.z = silu1(acc[a * 4 + 2] + cb * c3v.z + ba1v.z);
                t4.w = silu1(acc[a * 4 + 3] + cb * c3v.w + ba1v.w);
                *(float4*)&tbT[at0 + a][c0] = t4;
            }
        }
        BND("8"); stage16k(WaL + 3 * CHF, &wb[(6 * l + 5) & 3][0], tid);

        // GEMM2: h += t @ Wa2[l]
        float acc2[12] = {0,0,0,0,0,0,0,0,0,0,0,0};
        GEMM12(acc2, (&wb[(6 * l + 2) & 3][0]), tbT, 0);      // phase 6l+2
        BND("8"); stage16k(W3N, &wb[(6 * l + 6) & 3][0], tid);
        GEMM12(acc2, (&wb[(6 * l + 3) & 3][0]), tbT, 32);     // phase 6l+3
        BND("8"); stage16k(W3N + CHF, &wb[(6 * l + 7) & 3][0], tid);
        GEMM12(acc2, (&wb[(6 * l + 4) & 3][0]), tbT, 64);     // phase 6l+4
        BND("8"); stage16k(WaN, &wb[(6 * l + 8) & 3][0], tid);
        GEMM12(acc2, (&wb[(6 * l + 5) & 3][0]), tbT, 96);     // phase 6l+5
        #pragma unroll
        for (int a = 0; a < 3; ++a) {
            h[a * 4 + 0] += acc2[a * 4 + 0] + ba2v.x;
            h[a * 4 + 1] += acc2[a * 4 + 1] + ba2v.y;
            h[a * 4 + 2] += acc2[a * 4 + 2] + ba2v.z;
            h[a * 4 + 3] += acc2[a * 4 + 3] + ba2v.w;
        }
        BND("8");
        stage16k((l < LL - 1) ? (Wa2 + (l + 1) * HH * HH + CHF) : (Wo1 + 3 * CHF),
                 &wb[(6 * l + 9) & 3][0], tid);
    }

    // ---- stage h into tbT for the head ----
    #pragma unroll
    for (int a = 0; a < 3; ++a)
        *(float4*)&tbT[at0 + a][c0] = make_float4(h[a * 4 + 0], h[a * 4 + 1],
                                                  h[a * 4 + 2], h[a * 4 + 3]);
    asm volatile("s_waitcnt lgkmcnt(0)" ::: "memory");
    __builtin_amdgcn_s_barrier();
    __builtin_amdgcn_sched_barrier(0);

    // ---- output head: phases 18..21 (slots 2,3,0,1), epilogue waits 8/4/0 ----
    float acc[12] = {0,0,0,0,0,0,0,0,0,0,0,0};
    GEMM12(acc, (&wb[2][0]), tbT, 0);        // phase 18
    BND("8");
    GEMM12(acc, (&wb[3][0]), tbT, 32);       // phase 19
    BND("4");
    GEMM12(acc, (&wb[0][0]), tbT, 64);       // phase 20
    BND("0");
    GEMM12(acc, (&wb[1][0]), tbT, 96);       // phase 21

    // per-atom partial over this lane's 4 channels
    float p3[3];
    #pragma unroll
    for (int a = 0; a < 3; ++a) {
        p3[a] = silu1(acc[a * 4 + 0] + bo1R.x) * wo2R.x
              + silu1(acc[a * 4 + 1] + bo1R.y) * wo2R.y
              + silu1(acc[a * 4 + 2] + bo1R.z) * wo2R.z
              + silu1(acc[a * 4 + 3] + bo1R.w) * wo2R.w;
    }
    // reduce over the 32 cp-lanes within each half-wave
    #pragma unroll
    for (int a = 0; a < 3; ++a) {
        float r = p3[a];
        r += __shfl_down(r, 16); r += __shfl_down(r, 8);
        r += __shfl_down(r, 4);  r += __shfl_down(r, 2);
        r += __shfl_down(r, 1);
        p3[a] = r;
    }
    if ((q & 31) == 0) {
        #pragma unroll
        for (int a = 0; a < 3; ++a) po[2 * wv + ap][a] = p3[a];
    }
    __syncthreads();   // vmcnt already 0 -> no hidden drain cost
    if (tid == 0) {
        // atom j = 6wv+3ap+a -> po row j/3 = 2wv+ap, col j%3 = a
        float sum = 0.f;
        #pragma unroll
        for (int j = 0; j < AT; ++j) {
            if (lbase + j < nv) sum += po[j / 3][j % 3] + bo2R;
        }
        atomicAdd(out + b, sum / cb);
    }
}

extern "C" void kernel_launch(void* const* d_in, const int* in_sizes, int n_in,
                              void* d_out, int out_size, void* d_ws, size_t ws_size,
                              hipStream_t stream) {
    const float* X     = (const float*)d_in[0];
    const float* R     = (const float*)d_in[1];
    const int*   batch = (const int*)  d_in[2];
    const float* We    = (const float*)d_in[3];
    const float* be    = (const float*)d_in[4];
    const float* Wrbf  = (const float*)d_in[5];
    const float* brbf  = (const float*)d_in[6];
    const float* Wpair = (const float*)d_in[7];
    const float* bpair = (const float*)d_in[8];
    const float* Wa1   = (const float*)d_in[9];
    const float* ba1   = (const float*)d_in[10];
    const float* Wa2   = (const float*)d_in[11];
    const float* ba2   = (const float*)d_in[12];
    const float* Wo1   = (const float*)d_in[13];
    const float* bo1   = (const float*)d_in[14];
    const float* Wo2   = (const float*)d_in[15];
    const float* bo2   = (const float*)d_in[16];

    float* w    = (float*)d_ws;
    float* W3i  = w;                       // L*K*H  = 24576
    float* c3   = W3i + LL * KK * HH;      // L*H    = 384
    float* cnt  = c3 + LL * HH;            // B      = 64
    float* out  = (float*)d_out;

    hipLaunchKernelGGL(pre_kernel, dim3(W3_BLOCKS + CNT_BLOCKS), dim3(256),
                       0, stream, Wrbf, brbf, Wpair, bpair, Wa1, batch,
                       W3i, c3, cnt, out);
    hipLaunchKernelGGL(chain_kernel, dim3(BB * NN / AT), dim3(256), 0, stream,
                       X, R, We, be, ba1, ba2, bo1, Wo2, bo2,
                       W3i, Wa2, Wo1, c3, cnt, out);
}

// Round 17
// 40.469 us; speedup vs baseline: 1.3815x; 1.3815x over previous
//
#include <hip/hip_runtime.h>
#include <hip/hip_bf16.h>

#define BB 64
#define NN 96
#define FF 16
#define HH 128
#define KK 64
#define LL 3
#define CUTOFF_F 10.0f
#define GAMMA_F 10.0f

#define W3_BLOCKS 99
#define WA2_CP 12
#define WO1_CP 4
#define CNT_BLOCKS BB

// f16 chunk layout (32 k-rows x 128 ch = 4096 f16 = 8KB):
//   idx(k,ch) = ((k>>2)*64 + (ch>>1))*8 + (ch&1)*4 + (k&3)
// -> lane q reads b128 at ((kq*64+q)*8): {c0:k0..k3, c1:k0..k3} for ch-pair q.
#define F16IDX(k, ch) ((((k) >> 2) * 64 + ((ch) >> 1)) * 8 + (((ch) & 1) << 2) + ((k) & 3))

// ---------------------------------------------------------------------------
// pre_kernel:
//   [0,99):    W3 = (Wrbf@Wpair)@Wa1 rows -> f16 chunk layout (row 64 -> c3 fp32)
//   [99,111):  Wa2h = f16 chunk-relayout of Wa2
//   [111,115): Wo1h = f16 chunk-relayout of Wo1
//   [115,179): cnt[b]; zero out[b]
// ---------------------------------------------------------------------------
__global__ __launch_bounds__(256) void pre_kernel(
    const float* __restrict__ Wrbf, const float* __restrict__ brbf,
    const float* __restrict__ Wpair, const float* __restrict__ bpair,
    const float* __restrict__ Wa1, const float* __restrict__ Wa2,
    const float* __restrict__ Wo1,
    const int* __restrict__ batch,
    _Float16* __restrict__ W3h, float* __restrict__ c3,
    _Float16* __restrict__ Wa2h, _Float16* __restrict__ Wo1h,
    float* __restrict__ cnt, float* __restrict__ out)
{
    const int bid = blockIdx.x;
    const int tid = threadIdx.x;
    if (bid < W3_BLOCKS) {
        __shared__ float sW2[2][HH];
        const int l    = bid / 33;
        const int r0   = (bid % 33) * 2;
        const int half = tid >> 7;
        const int h    = tid & 127;
        const int kk   = r0 + half;       // 0..65 (65 inactive)
        const bool active = (kk <= KK);
        if (active) {
            const float* Wp = Wpair + l * HH * HH + h;
            const float* arow;
            float acc;
            if (kk < KK) { arow = Wrbf + (l * KK + kk) * HH; acc = 0.f; }
            else         { arow = brbf + l * HH;             acc = bpair[l * HH + h]; }
            #pragma unroll 8
            for (int m = 0; m < HH; ++m) acc += arow[m] * Wp[m * HH];
            sW2[half][h] = acc;
        }
        __syncthreads();
        if (active) {
            const float* Wa = Wa1 + l * HH * HH + h;
            const float* row = sW2[half];
            float a3 = 0.f;
            #pragma unroll 8
            for (int m = 0; m < HH; ++m) a3 += row[m] * Wa[m * HH];
            if (kk < KK)
                W3h[l * 8192 + (kk >> 5) * 4096 + F16IDX(kk & 31, h)] = (_Float16)a3;
            else
                c3[l * HH + h] = a3;
        }
    } else if (bid < W3_BLOCKS + WA2_CP + WO1_CP) {
        int ci = bid - W3_BLOCKS;
        const float* src;
        _Float16* dst;
        if (ci < WA2_CP) { src = Wa2 + ci * 4096; dst = Wa2h + ci * 4096; }
        else             { src = Wo1 + (ci - WA2_CP) * 4096; dst = Wo1h + (ci - WA2_CP) * 4096; }
        for (int e = tid; e < 4096; e += 256) {
            int k = e >> 7, hc = e & 127;
            dst[F16IDX(k, hc)] = (_Float16)src[e];
        }
    } else {
        int b = bid - (W3_BLOCKS + WA2_CP + WO1_CP);
        __shared__ int c[4];
        bool v = (tid < NN) && (batch[b * NN + tid] != -1);
        unsigned long long m = __ballot(v);
        if ((tid & 63) == 0) c[tid >> 6] = __popcll(m);
        __syncthreads();
        if (tid == 0) {
            cnt[b] = (float)(c[0] + c[1] + c[2] + c[3]);
            out[b] = 0.f;
        }
    }
}

// ---------------------------------------------------------------------------
// chain_kernel: R15-verified skeleton (AT=12, 256 thr, grid 512 = 2 blocks/CU,
// 4-slot ring, counted vmcnt, one s_barrier/phase, stage-after-barrier,
// unroll-1 layer loop) with f16 operands + v_dot2_f32_f16 (fp32 accumulate).
// Per 8-k group: 2 weight b128 + 3 operand broadcasts = 5 LDS reads / 24 fdot2
// (48 MACs). Chunks are 8KB -> 2 DMA loads/thread -> BND counts 6 / 4 / 4,2,0.
// ---------------------------------------------------------------------------
#define AT 12
#define CHF 4096              // f16 per 8KB chunk (32 k x 128 ch)
#define SSW 72                // sST row stride (f16)
#define TBW 136               // tbT row stride (f16)

typedef const __attribute__((address_space(1))) void* gp1_t;
typedef __attribute__((address_space(3))) void* lp3_t;

typedef _Float16 h2 __attribute__((ext_vector_type(2)));
union F4H { float4 f; h2 d[4]; };

__device__ __forceinline__ float fdot2w(h2 a, h2 b, float c) {
#if __has_builtin(__builtin_amdgcn_fdot2)
    return __builtin_amdgcn_fdot2(a, b, c, false);
#else
    return c + (float)a[0] * (float)b[0] + (float)a[1] * (float)b[1];
#endif
}

__device__ __forceinline__ void stage8k(const _Float16* g, _Float16* lds, int tid)
{
    #pragma unroll
    for (int j = 0; j < 2; ++j) {
        const int u = j * 256 + tid;      // float4 units; per-wave lane-contiguous
        __builtin_amdgcn_global_load_lds((gp1_t)(g + (size_t)u * 8),
                                         (lp3_t)(lds + (size_t)u * 8), 16, 0, 0);
    }
}

// phase boundary: publish loads (vmcnt<=N) + flush LDS writes, then barrier.
#define BND(VM) do {                                                        \
    asm volatile("s_waitcnt vmcnt(" VM ") lgkmcnt(0)" ::: "memory");        \
    __builtin_amdgcn_s_barrier();                                           \
    __builtin_amdgcn_sched_barrier(0);                                      \
} while (0)

__device__ __forceinline__ float silu1(float v) { return v / (1.f + __expf(-v)); }

// one 8KB chunk (32 k) of a GEMM. ACC[2a+c]: atom a (0..2), channel c (0..1)
#define GEMMD(ACC, WBP, SRC, KB) do {                                       \
    _Pragma("unroll")                                                       \
    for (int g8 = 0; g8 < 4; ++g8) {                                        \
        F4H w0, w1, u0, u1, u2;                                             \
        w0.f = *(const float4*)&(WBP)[((2 * g8 + 0) * 64 + q) * 8];         \
        w1.f = *(const float4*)&(WBP)[((2 * g8 + 1) * 64 + q) * 8];         \
        u0.f = *(const float4*)&SRC[at0 + 0][(KB) + 8 * g8];                \
        u1.f = *(const float4*)&SRC[at0 + 1][(KB) + 8 * g8];                \
        u2.f = *(const float4*)&SRC[at0 + 2][(KB) + 8 * g8];                \
        ACC[0] = fdot2w(u0.d[0], w0.d[0], ACC[0]);                          \
        ACC[0] = fdot2w(u0.d[1], w0.d[1], ACC[0]);                          \
        ACC[0] = fdot2w(u0.d[2], w1.d[0], ACC[0]);                          \
        ACC[0] = fdot2w(u0.d[3], w1.d[1], ACC[0]);                          \
        ACC[1] = fdot2w(u0.d[0], w0.d[2], ACC[1]);                          \
        ACC[1] = fdot2w(u0.d[1], w0.d[3], ACC[1]);                          \
        ACC[1] = fdot2w(u0.d[2], w1.d[2], ACC[1]);                          \
        ACC[1] = fdot2w(u0.d[3], w1.d[3], ACC[1]);                          \
        ACC[2] = fdot2w(u1.d[0], w0.d[0], ACC[2]);                          \
        ACC[2] = fdot2w(u1.d[1], w0.d[1], ACC[2]);                          \
        ACC[2] = fdot2w(u1.d[2], w1.d[0], ACC[2]);                          \
        ACC[2] = fdot2w(u1.d[3], w1.d[1], ACC[2]);                          \
        ACC[3] = fdot2w(u1.d[0], w0.d[2], ACC[3]);                          \
        ACC[3] = fdot2w(u1.d[1], w0.d[3], ACC[3]);                          \
        ACC[3] = fdot2w(u1.d[2], w1.d[2], ACC[3]);                          \
        ACC[3] = fdot2w(u1.d[3], w1.d[3], ACC[3]);                          \
        ACC[4] = fdot2w(u2.d[0], w0.d[0], ACC[4]);                          \
        ACC[4] = fdot2w(u2.d[1], w0.d[1], ACC[4]);                          \
        ACC[4] = fdot2w(u2.d[2], w1.d[0], ACC[4]);                          \
        ACC[4] = fdot2w(u2.d[3], w1.d[1], ACC[4]);                          \
        ACC[5] = fdot2w(u2.d[0], w0.d[2], ACC[5]);                          \
        ACC[5] = fdot2w(u2.d[1], w0.d[3], ACC[5]);                          \
        ACC[5] = fdot2w(u2.d[2], w1.d[2], ACC[5]);                          \
        ACC[5] = fdot2w(u2.d[3], w1.d[3], ACC[5]);                          \
    }                                                                       \
} while (0)

__global__ __launch_bounds__(256, 2) void chain_kernel(
    const float* __restrict__ X, const float* __restrict__ R,
    const float* __restrict__ We, const float* __restrict__ be,
    const float* __restrict__ ba1, const float* __restrict__ ba2,
    const float* __restrict__ bo1, const float* __restrict__ Wo2,
    const float* __restrict__ bo2, const _Float16* __restrict__ W3h,
    const _Float16* __restrict__ Wa2h, const _Float16* __restrict__ Wo1h,
    const float* __restrict__ c3, const float* __restrict__ cnt,
    float* __restrict__ out)
{
    __shared__ __align__(16) _Float16 wb[4][CHF];    // 32KB weight ring
    __shared__ __align__(16) _Float16 sST[AT][SSW];  // 1.7KB S (f16, persists)
    __shared__ __align__(16) _Float16 tbT[AT][TBW];  // 3.2KB t / h (f16)
    __shared__ __align__(16) float sX[FF][AT];       // 0.75KB
    __shared__ __align__(16) float sDf[AT * NN + NN * 3];  // 5.6KB dist + R
    __shared__ float po[4][3];

    const int tid  = threadIdx.x;
    const int q    = tid & 63;           // lane: channel pair c0=2q, c0+1
    const int wv   = tid >> 6;           // wave 0..3
    const int c0   = 2 * q;
    const int at0  = 3 * wv;             // this wave's atoms at0..at0+2
    const int a0   = blockIdx.x * AT;    // 96 % 12 == 0 -> block within one molecule
    const int b    = a0 / NN;
    const int lbase = a0 - b * NN;       // molecule-local first atom
    const float cb = cnt[b];
    const int nv   = (int)cb;            // valid atoms = molecule-local prefix

    float* sD  = sDf;                    // AT*NN distances
    float* sRf = sDf + AT * NN;          // molecule R

    // ---- stage molecule R, X^T ----
    for (int t = tid; t < NN * 3; t += 256) sRf[t] = R[b * NN * 3 + t];
    if (tid < AT * FF) {
        int a = tid >> 4, f = tid & 15;
        sX[f][a] = X[(a0 + a) * FF + f];
    }
    __syncthreads();

    // ---- phase 1: distance table D[j][i] ----
    for (int e = tid; e < AT * NN; e += 256) {
        int j = e / NN, i = e - j * NN;
        float dx = sRf[i * 3 + 0] - sRf[(lbase + j) * 3 + 0];
        float dy = sRf[i * 3 + 1] - sRf[(lbase + j) * 3 + 1];
        float dz = sRf[i * 3 + 2] - sRf[(lbase + j) * 3 + 2];
        sD[e] = sqrtf(dx * dx + dy * dy + dz * dz);
    }
    __syncthreads();   // no DMA outstanding yet -> cheap

    // ---- bias preloads + embedding (all global loads OLDER than chunk DMAs) ----
    const float2 beR  = *(const float2*)&be[c0];
    const float2 bo1R = *(const float2*)&bo1[c0];
    const float2 wo2R = *(const float2*)&Wo2[c0];
    const float  bo2R = bo2[0];
    const float2 c3R0 = *(const float2*)&c3[0 * HH + c0];
    const float2 c3R1 = *(const float2*)&c3[1 * HH + c0];
    const float2 c3R2 = *(const float2*)&c3[2 * HH + c0];
    const float2 ba1R0 = *(const float2*)&ba1[0 * HH + c0];
    const float2 ba1R1 = *(const float2*)&ba1[1 * HH + c0];
    const float2 ba1R2 = *(const float2*)&ba1[2 * HH + c0];
    const float2 ba2R0 = *(const float2*)&ba2[0 * HH + c0];
    const float2 ba2R1 = *(const float2*)&ba2[1 * HH + c0];
    const float2 ba2R2 = *(const float2*)&ba2[2 * HH + c0];

    float h[6];
    {
        float acc[6] = {0, 0, 0, 0, 0, 0};
        const float* wp = We + c0;
        #pragma unroll
        for (int f = 0; f < FF; ++f) {
            float2 w2 = *(const float2*)&wp[f * HH];
            #pragma unroll
            for (int a = 0; a < 3; ++a) {
                float x = sX[f][at0 + a];
                acc[2 * a + 0] += w2.x * x;
                acc[2 * a + 1] += w2.y * x;
            }
        }
        #pragma unroll
        for (int a = 0; a < 3; ++a) {
            h[2 * a + 0] = acc[2 * a + 0] + beR.x;
            h[2 * a + 1] = acc[2 * a + 1] + beR.y;
        }
    }

    // ---- prologue: issue chunks 0..3 (hidden under S-phase) ----
    stage8k(W3h,        wb[0], tid);     // chunk 0: W3[0] k 0-31
    stage8k(W3h + CHF,  wb[1], tid);     // chunk 1: W3[0] k 32-63
    stage8k(Wa2h,       wb[2], tid);     // chunk 2: Wa2[0] m 0-31
    stage8k(Wa2h + CHF, wb[3], tid);     // chunk 3: Wa2[0] m 32-63

    // ---- phase 2: sST[j][k] = (f16) sum_{i<nv} exp(-g*(D[j][i]-ck)^2) ----
    {
        const int k = q;
        const float ck = (float)k * (CUTOFF_F / (float)(KK - 1));
        #pragma unroll
        for (int r = 0; r < 3; ++r) {
            int j = 3 * wv + r;              // wave-uniform; == at0+r
            if (lbase + j >= nv) { sST[j][k] = (_Float16)0.f; continue; }
            const float* Dr = sD + j * NN;
            float acc = 0.f;
            for (int i = 0; i < nv; ++i) {
                float u = Dr[i] - ck;
                acc += __expf(-GAMMA_F * u * u);
            }
            sST[j][k] = (_Float16)acc;
        }
    }

    BND("6");   // 8 stage loads out; <=6 -> chunk 0 landed (1,2,3 in flight)

    // ---- layers: phases 6l+0 .. 6l+5 (NOT unrolled -> no spills) ----
    #pragma unroll 1
    for (int l = 0; l < LL; ++l) {
        const float2 c3v  = (l == 0) ? c3R0  : (l == 1) ? c3R1  : c3R2;
        const float2 ba1v = (l == 0) ? ba1R0 : (l == 1) ? ba1R1 : ba1R2;
        const float2 ba2v = (l == 0) ? ba2R0 : (l == 1) ? ba2R1 : ba2R2;
        const _Float16* WaN = (l < LL - 1) ? (Wa2h + (l + 1) * 4 * CHF) : (Wo1h + 2 * CHF);
        const _Float16* W3N = (l < LL - 1) ? (W3h + (l + 1) * 2 * CHF) : Wo1h;
        const _Float16* WaL = Wa2h + l * 4 * CHF;

        // GEMM1: acc = S @ W3[l]
        float acc[6] = {0, 0, 0, 0, 0, 0};
        GEMMD(acc, (&wb[(6 * l + 0) & 3][0]), sST, 0);        // phase 6l+0
        BND("4"); stage8k(WaL + 2 * CHF, &wb[(6 * l + 4) & 3][0], tid);
        GEMMD(acc, (&wb[(6 * l + 1) & 3][0]), sST, 32);       // phase 6l+1
        {   // silu -> tbT f16 (owned (atom, ch-pair) cells; last readers done)
            #pragma unroll
            for (int a = 0; a < 3; ++a) {
                h2 t2;
                t2[0] = (_Float16)silu1(acc[2 * a + 0] + cb * c3v.x + ba1v.x);
                t2[1] = (_Float16)silu1(acc[2 * a + 1] + cb * c3v.y + ba1v.y);
                *(h2*)&tbT[at0 + a][c0] = t2;
            }
        }
        BND("4"); stage8k(WaL + 3 * CHF, &wb[(6 * l + 5) & 3][0], tid);

        // GEMM2: h += t @ Wa2[l]
        float acc2[6] = {0, 0, 0, 0, 0, 0};
        GEMMD(acc2, (&wb[(6 * l + 2) & 3][0]), tbT, 0);       // phase 6l+2
        BND("4"); stage8k(W3N, &wb[(6 * l + 6) & 3][0], tid);
        GEMMD(acc2, (&wb[(6 * l + 3) & 3][0]), tbT, 32);      // phase 6l+3
        BND("4"); stage8k(W3N + CHF, &wb[(6 * l + 7) & 3][0], tid);
        GEMMD(acc2, (&wb[(6 * l + 4) & 3][0]), tbT, 64);      // phase 6l+4
        BND("4"); stage8k(WaN, &wb[(6 * l + 8) & 3][0], tid);
        GEMMD(acc2, (&wb[(6 * l + 5) & 3][0]), tbT, 96);      // phase 6l+5
        #pragma unroll
        for (int a = 0; a < 3; ++a) {
            h[2 * a + 0] += acc2[2 * a + 0] + ba2v.x;
            h[2 * a + 1] += acc2[2 * a + 1] + ba2v.y;
        }
        BND("4");
        stage8k((l < LL - 1) ? (Wa2h + (l + 1) * 4 * CHF + CHF) : (Wo1h + 3 * CHF),
                &wb[(6 * l + 9) & 3][0], tid);
    }

    // ---- stage h into tbT (f16) for the head ----
    #pragma unroll
    for (int a = 0; a < 3; ++a) {
        h2 t2;
        t2[0] = (_Float16)h[2 * a + 0];
        t2[1] = (_Float16)h[2 * a + 1];
        *(h2*)&tbT[at0 + a][c0] = t2;
    }
    asm volatile("s_waitcnt lgkmcnt(0)" ::: "memory");
    __builtin_amdgcn_s_barrier();
    __builtin_amdgcn_sched_barrier(0);

    // ---- output head: phases 18..21 (slots 2,3,0,1), epilogue waits 4/2/0 ----
    float acc[6] = {0, 0, 0, 0, 0, 0};
    GEMMD(acc, (&wb[2][0]), tbT, 0);         // phase 18
    BND("4");
    GEMMD(acc, (&wb[3][0]), tbT, 32);        // phase 19
    BND("2");
    GEMMD(acc, (&wb[0][0]), tbT, 64);        // phase 20
    BND("0");
    GEMMD(acc, (&wb[1][0]), tbT, 96);        // phase 21

    // per-atom partial over this lane's 2 channels; wave covers all 128
    float p3[3];
    #pragma unroll
    for (int a = 0; a < 3; ++a) {
        p3[a] = silu1(acc[2 * a + 0] + bo1R.x) * wo2R.x
              + silu1(acc[2 * a + 1] + bo1R.y) * wo2R.y;
    }
    #pragma unroll
    for (int a = 0; a < 3; ++a) {
        float r = p3[a];
        r += __shfl_down(r, 32); r += __shfl_down(r, 16);
        r += __shfl_down(r, 8);  r += __shfl_down(r, 4);
        r += __shfl_down(r, 2);  r += __shfl_down(r, 1);
        p3[a] = r;
    }
    if (q == 0) {
        #pragma unroll
        for (int a = 0; a < 3; ++a) po[wv][a] = p3[a];   // atom at0+a fully reduced
    }
    __syncthreads();   // vmcnt already 0 -> no hidden drain cost
    if (tid == 0) {
        float sum = 0.f;
        #pragma unroll
        for (int j = 0; j < AT; ++j) {
            if (lbase + j < nv) sum += po[j / 3][j % 3] + bo2R;
        }
        atomicAdd(out + b, sum / cb);
    }
}

extern "C" void kernel_launch(void* const* d_in, const int* in_sizes, int n_in,
                              void* d_out, int out_size, void* d_ws, size_t ws_size,
                              hipStream_t stream) {
    const float* X     = (const float*)d_in[0];
    const float* R     = (const float*)d_in[1];
    const int*   batch = (const int*)  d_in[2];
    const float* We    = (const float*)d_in[3];
    const float* be    = (const float*)d_in[4];
    const float* Wrbf  = (const float*)d_in[5];
    const float* brbf  = (const float*)d_in[6];
    const float* Wpair = (const float*)d_in[7];
    const float* bpair = (const float*)d_in[8];
    const float* Wa1   = (const float*)d_in[9];
    const float* ba1   = (const float*)d_in[10];
    const float* Wa2   = (const float*)d_in[11];
    const float* ba2   = (const float*)d_in[12];
    const float* Wo1   = (const float*)d_in[13];
    const float* bo1   = (const float*)d_in[14];
    const float* Wo2   = (const float*)d_in[15];
    const float* bo2   = (const float*)d_in[16];

    char* wsb = (char*)d_ws;
    _Float16* W3h  = (_Float16*)wsb;                              // 24576 f16 = 49152 B
    float*    c3   = (float*)(wsb + 49152);                       // 384 f32  = 1536 B
    _Float16* Wa2h = (_Float16*)(wsb + 49152 + 1536);             // 49152 f16 = 98304 B
    _Float16* Wo1h = (_Float16*)(wsb + 49152 + 1536 + 98304);     // 16384 f16 = 32768 B
    float*    cnt  = (float*)(wsb + 49152 + 1536 + 98304 + 32768);// 64 f32
    float*    out  = (float*)d_out;

    hipLaunchKernelGGL(pre_kernel,
                       dim3(W3_BLOCKS + WA2_CP + WO1_CP + CNT_BLOCKS), dim3(256),
                       0, stream, Wrbf, brbf, Wpair, bpair, Wa1, Wa2, Wo1, batch,
                       W3h, c3, Wa2h, Wo1h, cnt, out);
    hipLaunchKernelGGL(chain_kernel, dim3(BB * NN / AT), dim3(256), 0, stream,
                       X, R, We, be, ba1, ba2, bo1, Wo2, bo2,
                       W3h, Wa2h, Wo1h, c3, cnt, out);
}

// Round 18
// 30.691 us; speedup vs baseline: 1.8216x; 1.3186x over previous
//
#include <hip/hip_runtime.h>
#include <hip/hip_bf16.h>

#define BB 64
#define NN 96
#define FF 16
#define HH 128
#define KK 64
#define LL 3
#define CUTOFF_F 10.0f
#define GAMMA_F 10.0f

#define W3_BLOCKS 99
#define WA2_CP 12
#define WO1_CP 4
#define WE_CP 1
#define CNT_BLOCKS BB

// Weight storage: f16, column-major [ch][k] per 16KB chunk (128ch x 64k),
// XOR-swizzled so the swizzled-read is bank-conflict-free after a LINEAR DMA:
//   SWZ(ch,k) = ch*64 + (k ^ ((ch&7)<<3))      (f16 units within a chunk)
#define SWZ(ch, k) ((ch) * 64 + ((k) ^ (((ch) & 7) << 3)))

// ---------------------------------------------------------------------------
// pre_kernel:
//   [0,99):    W3 = (Wrbf@Wpair)@Wa1 -> f16 [ch][k] swizzled chunks; row64->c3
//   [99,111):  Wa2c: f16 relayout of Wa2 (2 chunks/layer: k 0-63, 64-127)
//   [111,115): Wo1c: same for Wo1
//   [115,116): Wec:  f16 [ch][f] relayout of We (no swizzle; read direct)
//   [116,180): cnt[b]; zero out[b]
// ---------------------------------------------------------------------------
__global__ __launch_bounds__(256) void pre_kernel(
    const float* __restrict__ Wrbf, const float* __restrict__ brbf,
    const float* __restrict__ Wpair, const float* __restrict__ bpair,
    const float* __restrict__ Wa1, const float* __restrict__ Wa2,
    const float* __restrict__ Wo1, const float* __restrict__ We,
    const int* __restrict__ batch,
    _Float16* __restrict__ W3c, float* __restrict__ c3,
    _Float16* __restrict__ Wa2c, _Float16* __restrict__ Wo1c,
    _Float16* __restrict__ Wec,
    float* __restrict__ cnt, float* __restrict__ out)
{
    const int bid = blockIdx.x;
    const int tid = threadIdx.x;
    if (bid < W3_BLOCKS) {
        __shared__ float sW2[2][HH];
        const int l    = bid / 33;
        const int r0   = (bid % 33) * 2;
        const int half = tid >> 7;
        const int h    = tid & 127;
        const int kk   = r0 + half;       // 0..65 (65 inactive)
        const bool active = (kk <= KK);
        if (active) {
            const float* Wp = Wpair + l * HH * HH + h;
            const float* arow;
            float acc;
            if (kk < KK) { arow = Wrbf + (l * KK + kk) * HH; acc = 0.f; }
            else         { arow = brbf + l * HH;             acc = bpair[l * HH + h]; }
            #pragma unroll 8
            for (int m = 0; m < HH; ++m) acc += arow[m] * Wp[m * HH];
            sW2[half][h] = acc;
        }
        __syncthreads();
        if (active) {
            const float* Wa = Wa1 + l * HH * HH + h;
            const float* row = sW2[half];
            float a3 = 0.f;
            #pragma unroll 8
            for (int m = 0; m < HH; ++m) a3 += row[m] * Wa[m * HH];
            if (kk < KK) W3c[l * 8192 + SWZ(h, kk)] = (_Float16)a3;  // B[k][ch] -> [ch][k]
            else         c3[l * HH + h] = a3;
        }
    } else if (bid < W3_BLOCKS + WA2_CP) {
        int ci = bid - W3_BLOCKS;                 // 4096 f32 elems each
        for (int e = tid; e < 4096; e += 256) {
            int E = ci * 4096 + e;                // Wa2 flat [l][k][ch]
            int l = E / 16384, r = E % 16384;
            int k = r >> 7, ch = r & 127;
            Wa2c[l * 16384 + (k >> 6) * 8192 + SWZ(ch, k & 63)] = (_Float16)Wa2[E];
        }
    } else if (bid < W3_BLOCKS + WA2_CP + WO1_CP) {
        int ci = bid - W3_BLOCKS - WA2_CP;
        for (int e = tid; e < 4096; e += 256) {
            int E = ci * 4096 + e;                // Wo1 flat [k][ch]
            int k = E >> 7, ch = E & 127;
            Wo1c[(k >> 6) * 8192 + SWZ(ch, k & 63)] = (_Float16)Wo1[E];
        }
    } else if (bid < W3_BLOCKS + WA2_CP + WO1_CP + WE_CP) {
        for (int e = tid; e < FF * HH; e += 256) {
            int f = e >> 7, ch = e & 127;         // We [f][ch] -> Wec [ch][f]
            Wec[ch * FF + f] = (_Float16)We[e];
        }
    } else {
        int b = bid - (W3_BLOCKS + WA2_CP + WO1_CP + WE_CP);
        __shared__ int c[4];
        bool v = (tid < NN) && (batch[b * NN + tid] != -1);
        unsigned long long m = __ballot(v);
        if ((tid & 63) == 0) c[tid >> 6] = __popcll(m);
        __syncthreads();
        if (tid == 0) {
            cnt[b] = (float)(c[0] + c[1] + c[2] + c[3]);
            out[b] = 0.f;
        }
    }
}

// ---------------------------------------------------------------------------
// chain_kernel: MFMA version. AT=12 (padded to M=16), 256 thr (4 waves),
// grid 512 = 2 blocks/CU. Wave wv owns ch columns [32wv, 32wv+32) as two
// 16-wide tiles. v_mfma_f32_16x16x32_f16; A row=lane&15, k=(lane>>4)*8+j;
// B col=lane&15, same k; D col=lane&15, row=(lane>>4)*4+r (m89-verified).
// Weight ring: 4 x 16KB, counted vmcnt (12 prologue / 8 loop / 4,0 epilogue),
// one s_barrier per phase, stage-after-barrier (R15-proven skeleton).
// ---------------------------------------------------------------------------
#define AT 12

typedef const __attribute__((address_space(1))) void* gp1_t;
typedef __attribute__((address_space(3))) void* lp3_t;
typedef _Float16 h8 __attribute__((ext_vector_type(8)));
typedef float f32x4 __attribute__((ext_vector_type(4)));

__device__ __forceinline__ void stage16(const _Float16* g, _Float16* lds, int tid)
{
    #pragma unroll
    for (int j = 0; j < 4; ++j) {
        const int u = j * 256 + tid;             // 16B units
        __builtin_amdgcn_global_load_lds((gp1_t)(g + (size_t)u * 8),
                                         (lp3_t)(lds + (size_t)u * 8), 16, 0, 0);
    }
}

#define BND(VM) do {                                                        \
    asm volatile("s_waitcnt vmcnt(" VM ") lgkmcnt(0)" ::: "memory");        \
    __builtin_amdgcn_s_barrier();                                           \
    __builtin_amdgcn_sched_barrier(0);                                      \
} while (0)

__device__ __forceinline__ float silu1(float v) { return v / (1.f + __expf(-v)); }

// B-fragment load from a swizzled chunk: ch = column, KB = k base (0 or 32)
#define LDB(WC, CH, KB) (*(const h8*)&(WC)[(CH) * 64 + (((KB) + lg8) ^ (((CH) & 7) << 3))])
#define MFMA(A, B, C) __builtin_amdgcn_mfma_f32_16x16x32_f16((A), (B), (C), 0, 0, 0)

__global__ __launch_bounds__(256, 2) void chain_kernel(
    const float* __restrict__ X, const float* __restrict__ R,
    const float* __restrict__ be,
    const float* __restrict__ ba1, const float* __restrict__ ba2,
    const float* __restrict__ bo1, const float* __restrict__ Wo2,
    const float* __restrict__ bo2, const _Float16* __restrict__ W3c,
    const _Float16* __restrict__ Wa2c, const _Float16* __restrict__ Wo1c,
    const _Float16* __restrict__ Wec,
    const float* __restrict__ c3, const float* __restrict__ cnt,
    float* __restrict__ out)
{
    __shared__ __align__(16) _Float16 wb[4 * 8192];       // 64KB weight ring
    __shared__ __align__(16) _Float16 sST[16][72];        // 2.3KB S (rows 12-15 zero)
    __shared__ __align__(16) _Float16 thbuf[2 * 16 * 136];// 8.7KB tbT+hbT (sD/sRf alias)
    __shared__ __align__(16) _Float16 sXh[16][32];        // 1KB X f16 (zero-padded)
    __shared__ float po[4][16];

    _Float16 (*tbT)[136] = (_Float16(*)[136])thbuf;
    _Float16 (*hbT)[136] = (_Float16(*)[136])(thbuf + 16 * 136);
    float* sD  = (float*)thbuf;          // 1152 floats (4608B of 8704B region)
    float* sRf = sD + AT * NN;           // 288 floats

    const int tid  = threadIdx.x;
    const int lane = tid & 63;
    const int wv   = tid >> 6;           // wave 0..3
    const int l15  = lane & 15;
    const int lg   = lane >> 4;          // lane group 0..3
    const int lg8  = lg * 8;
    const int lg4  = lg * 4;
    const int a0   = blockIdx.x * AT;    // 96 % 12 == 0 -> block within one molecule
    const int b    = a0 / NN;
    const int lbase = a0 - b * NN;
    const float cb = cnt[b];
    const int nv   = (int)cb;

    const int chA = 32 * wv + l15;       // this lane's two output columns
    const int chB = chA + 16;

    // ---- stage molecule R, X (f16, zero-padded rows/cols) ----
    for (int t = tid; t < NN * 3; t += 256) sRf[t] = R[b * NN * 3 + t];
    for (int t = tid; t < 512; t += 256) {
        int row = t >> 5, col = t & 31;
        float v = (row < AT && col < FF) ? X[(a0 + row) * FF + col] : 0.f;
        sXh[row][col] = (_Float16)v;
    }
    __syncthreads();

    // ---- phase 1: distance table D[j][i] ----
    for (int e = tid; e < AT * NN; e += 256) {
        int j = e / NN, i = e - j * NN;
        float dx = sRf[i * 3 + 0] - sRf[(lbase + j) * 3 + 0];
        float dy = sRf[i * 3 + 1] - sRf[(lbase + j) * 3 + 1];
        float dz = sRf[i * 3 + 2] - sRf[(lbase + j) * 3 + 2];
        sD[e] = sqrtf(dx * dx + dy * dy + dz * dz);
    }
    __syncthreads();   // no DMA outstanding yet

    // ---- bias scalars + embedding B-frag (global loads OLDER than DMAs) ----
    const float be_a = be[chA], be_b = be[chB];
    const float bo1_a = bo1[chA], bo1_b = bo1[chB];
    const float wo2_a = Wo2[chA], wo2_b = Wo2[chB];
    const float bo2R = bo2[0];
    const float c3_0a = c3[chA], c3_0b = c3[chB];
    const float c3_1a = c3[HH + chA], c3_1b = c3[HH + chB];
    const float c3_2a = c3[2 * HH + chA], c3_2b = c3[2 * HH + chB];
    const float ba1_0a = ba1[chA], ba1_0b = ba1[chB];
    const float ba1_1a = ba1[HH + chA], ba1_1b = ba1[HH + chB];
    const float ba1_2a = ba1[2 * HH + chA], ba1_2b = ba1[2 * HH + chB];
    const float ba2_0a = ba2[chA], ba2_0b = ba2[chB];
    const float ba2_1a = ba2[HH + chA], ba2_1b = ba2[HH + chB];
    const float ba2_2a = ba2[2 * HH + chA], ba2_2b = ba2[2 * HH + chB];
    h8 weA = (h8)(_Float16)0.f, weB = (h8)(_Float16)0.f;
    if (lg < 2) {                         // k = lg8..lg8+7 < 16 real features
        weA = *(const h8*)&Wec[chA * FF + lg8];
        weB = *(const h8*)&Wec[chB * FF + lg8];
    }

    // ---- prologue: issue chunks 0..3 ----
    stage16(W3c,          wb + 0 * 8192, tid);   // c0: W3[0]
    stage16(Wa2c,         wb + 1 * 8192, tid);   // c1: Wa2[0] k0-63
    stage16(Wa2c + 8192,  wb + 2 * 8192, tid);   // c2: Wa2[0] k64-127
    stage16(W3c + 8192,   wb + 3 * 8192, tid);   // c3: W3[1]

    // ---- phase 2: sST[j][k] (f16); zero pad rows 12-15 ----
    {
        const float ck = (float)lane * (CUTOFF_F / (float)(KK - 1));
        #pragma unroll
        for (int r = 0; r < 3; ++r) {
            int j = 3 * wv + r;              // wave-uniform
            if (lbase + j >= nv) { sST[j][lane] = (_Float16)0.f; continue; }
            const float* Dr = sD + j * NN;
            float acc = 0.f;
            for (int i = 0; i < nv; ++i) {
                float u = Dr[i] - ck;
                acc += __expf(-GAMMA_F * u * u);
            }
            sST[j][lane] = (_Float16)acc;
        }
        sST[12 + wv][lane] = (_Float16)0.f;
    }

    // ---- embedding via MFMA: h = X@We + be (K=32, zero-padded) ----
    f32x4 hA, hB;
    {
        f32x4 z = {0.f, 0.f, 0.f, 0.f};
        h8 xa = *(const h8*)&sXh[l15][lg8];
        hA = MFMA(xa, weA, z);
        hB = MFMA(xa, weB, z);
        #pragma unroll
        for (int r = 0; r < 4; ++r) { hA[r] += be_a; hB[r] += be_b; }
    }

    BND("12");   // c0 landed (c1..c3 in flight)

    // ---- layers: 3 phases each ----
    #pragma unroll 1
    for (int l = 0; l < LL; ++l) {
        const float c3a  = (l == 0) ? c3_0a  : (l == 1) ? c3_1a  : c3_2a;
        const float c3b  = (l == 0) ? c3_0b  : (l == 1) ? c3_1b  : c3_2b;
        const float ba1a = (l == 0) ? ba1_0a : (l == 1) ? ba1_1a : ba1_2a;
        const float ba1b = (l == 0) ? ba1_0b : (l == 1) ? ba1_1b : ba1_2b;
        const float ba2a = (l == 0) ? ba2_0a : (l == 1) ? ba2_1a : ba2_2a;
        const float ba2b = (l == 0) ? ba2_0b : (l == 1) ? ba2_1b : ba2_2b;
        // chunk indices: 3l (W3), 3l+1, 3l+2 (Wa2 halves); stages 3l+4..3l+6
        const int c_g1 = 3 * l;

        // GEMM1: agg = S @ W3[l]  (K=64)
        f32x4 accA, accB;
        {
            f32x4 z = {0.f, 0.f, 0.f, 0.f};
            const _Float16* wc = wb + (size_t)(c_g1 & 3) * 8192;
            h8 s0 = *(const h8*)&sST[l15][lg8];
            h8 s1 = *(const h8*)&sST[l15][32 + lg8];
            accA = MFMA(s0, LDB(wc, chA, 0), z);
            accA = MFMA(s1, LDB(wc, chA, 32), accA);
            accB = MFMA(s0, LDB(wc, chB, 0), z);
            accB = MFMA(s1, LDB(wc, chB, 32), accB);
        }
        {   // bias + silu -> tbT (D layout: row = lg4+r, col = chA/chB)
            float biasA = cb * c3a + ba1a, biasB = cb * c3b + ba1b;
            #pragma unroll
            for (int r = 0; r < 4; ++r) {
                tbT[lg4 + r][chA] = (_Float16)silu1(accA[r] + biasA);
                tbT[lg4 + r][chB] = (_Float16)silu1(accB[r] + biasB);
            }
        }
        BND("8");
        { int i = c_g1 + 4; if (i < 11) {
            const _Float16* p = (i >= 9) ? (Wo1c + (size_t)(i - 9) * 8192)
                : ((i % 3) == 0 ? (W3c + (size_t)(i / 3) * 8192)
                                : (Wa2c + (size_t)(i / 3) * 16384 + (size_t)(i % 3 - 1) * 8192));
            stage16(p, wb + (size_t)(i & 3) * 8192, tid); } }

        // GEMM2a: h += t @ Wa2[l], k 0..63
        {
            const _Float16* wc = wb + (size_t)((c_g1 + 1) & 3) * 8192;
            h8 t0 = *(const h8*)&tbT[l15][lg8];
            h8 t1 = *(const h8*)&tbT[l15][32 + lg8];
            hA = MFMA(t0, LDB(wc, chA, 0), hA);
            hA = MFMA(t1, LDB(wc, chA, 32), hA);
            hB = MFMA(t0, LDB(wc, chB, 0), hB);
            hB = MFMA(t1, LDB(wc, chB, 32), hB);
        }
        BND("8");
        { int i = c_g1 + 5; if (i < 11) {
            const _Float16* p = (i >= 9) ? (Wo1c + (size_t)(i - 9) * 8192)
                : ((i % 3) == 0 ? (W3c + (size_t)(i / 3) * 8192)
                                : (Wa2c + (size_t)(i / 3) * 16384 + (size_t)(i % 3 - 1) * 8192));
            stage16(p, wb + (size_t)(i & 3) * 8192, tid); } }

        // GEMM2b: h += t @ Wa2[l], k 64..127
        {
            const _Float16* wc = wb + (size_t)((c_g1 + 2) & 3) * 8192;
            h8 t2 = *(const h8*)&tbT[l15][64 + lg8];
            h8 t3 = *(const h8*)&tbT[l15][96 + lg8];
            hA = MFMA(t2, LDB(wc, chA, 0), hA);
            hA = MFMA(t3, LDB(wc, chA, 32), hA);
            hB = MFMA(t2, LDB(wc, chB, 0), hB);
            hB = MFMA(t3, LDB(wc, chB, 32), hB);
        }
        #pragma unroll
        for (int r = 0; r < 4; ++r) { hA[r] += ba2a; hB[r] += ba2b; }
        if (l == LL - 1) {
            #pragma unroll
            for (int r = 0; r < 4; ++r) {
                hbT[lg4 + r][chA] = (_Float16)hA[r];
                hbT[lg4 + r][chB] = (_Float16)hB[r];
            }
        }
        BND("8");
        { int i = c_g1 + 6; if (i < 11) {
            const _Float16* p = (i >= 9) ? (Wo1c + (size_t)(i - 9) * 8192)
                : ((i % 3) == 0 ? (W3c + (size_t)(i / 3) * 8192)
                                : (Wa2c + (size_t)(i / 3) * 16384 + (size_t)(i % 3 - 1) * 8192));
            stage16(p, wb + (size_t)(i & 3) * 8192, tid); } }
    }

    // ---- head: O = h @ Wo1 (chunks 9,10 in slots 1,2) ----
    BND("4");    // c9 landed
    f32x4 oA, oB;
    {
        f32x4 z = {0.f, 0.f, 0.f, 0.f};
        const _Float16* wc = wb + 1 * 8192;
        h8 a0 = *(const h8*)&hbT[l15][lg8];
        h8 a1 = *(const h8*)&hbT[l15][32 + lg8];
        oA = MFMA(a0, LDB(wc, chA, 0), z);
        oA = MFMA(a1, LDB(wc, chA, 32), oA);
        oB = MFMA(a0, LDB(wc, chB, 0), z);
        oB = MFMA(a1, LDB(wc, chB, 32), oB);
    }
    BND("0");    // c10 landed
    {
        const _Float16* wc = wb + 2 * 8192;
        h8 a2 = *(const h8*)&hbT[l15][64 + lg8];
        h8 a3 = *(const h8*)&hbT[l15][96 + lg8];
        oA = MFMA(a2, LDB(wc, chA, 0), oA);
        oA = MFMA(a3, LDB(wc, chA, 32), oA);
        oB = MFMA(a2, LDB(wc, chB, 0), oB);
        oB = MFMA(a3, LDB(wc, chB, 32), oB);
    }

    // ---- epilogue: silu, Wo2 dot, reduce over channels ----
    float p[4];
    #pragma unroll
    for (int r = 0; r < 4; ++r)
        p[r] = silu1(oA[r] + bo1_a) * wo2_a + silu1(oB[r] + bo1_b) * wo2_b;
    #pragma unroll
    for (int r = 0; r < 4; ++r) {
        p[r] += __shfl_xor(p[r], 1);
        p[r] += __shfl_xor(p[r], 2);
        p[r] += __shfl_xor(p[r], 4);
        p[r] += __shfl_xor(p[r], 8);
    }
    if (l15 == 0) {
        #pragma unroll
        for (int r = 0; r < 4; ++r) po[wv][lg4 + r] = p[r];  // atom = lg4+r
    }
    __syncthreads();
    if (tid == 0) {
        float sum = 0.f;
        #pragma unroll
        for (int j = 0; j < AT; ++j) {
            if (lbase + j < nv)
                sum += po[0][j] + po[1][j] + po[2][j] + po[3][j] + bo2R;
        }
        atomicAdd(out + b, sum / cb);
    }
}

extern "C" void kernel_launch(void* const* d_in, const int* in_sizes, int n_in,
                              void* d_out, int out_size, void* d_ws, size_t ws_size,
                              hipStream_t stream) {
    const float* X     = (const float*)d_in[0];
    const float* R     = (const float*)d_in[1];
    const int*   batch = (const int*)  d_in[2];
    const float* We    = (const float*)d_in[3];
    const float* be    = (const float*)d_in[4];
    const float* Wrbf  = (const float*)d_in[5];
    const float* brbf  = (const float*)d_in[6];
    const float* Wpair = (const float*)d_in[7];
    const float* bpair = (const float*)d_in[8];
    const float* Wa1   = (const float*)d_in[9];
    const float* ba1   = (const float*)d_in[10];
    const float* Wa2   = (const float*)d_in[11];
    const float* ba2   = (const float*)d_in[12];
    const float* Wo1   = (const float*)d_in[13];
    const float* bo1   = (const float*)d_in[14];
    const float* Wo2   = (const float*)d_in[15];
    const float* bo2   = (const float*)d_in[16];

    char* wsb = (char*)d_ws;
    _Float16* W3c  = (_Float16*)wsb;                         // 24576 f16 = 49152 B
    _Float16* Wa2c = (_Float16*)(wsb + 49152);               // 49152 f16 = 98304 B
    _Float16* Wo1c = (_Float16*)(wsb + 147456);              // 16384 f16 = 32768 B
    _Float16* Wec  = (_Float16*)(wsb + 180224);              // 2048 f16  = 4096 B
    float*    c3   = (float*)(wsb + 184320);                 // 384 f32   = 1536 B
    float*    cnt  = (float*)(wsb + 185856);                 // 64 f32
    float*    out  = (float*)d_out;

    hipLaunchKernelGGL(pre_kernel,
                       dim3(W3_BLOCKS + WA2_CP + WO1_CP + WE_CP + CNT_BLOCKS), dim3(256),
                       0, stream, Wrbf, brbf, Wpair, bpair, Wa1, Wa2, Wo1, We, batch,
                       W3c, c3, Wa2c, Wo1c, Wec, cnt, out);
    hipLaunchKernelGGL(chain_kernel, dim3(BB * NN / AT), dim3(256), 0, stream,
                       X, R, be, ba1, ba2, bo1, Wo2, bo2,
                       W3c, Wa2c, Wo1c, Wec, c3, cnt, out);
}